// Round 3
// baseline (16153.961 us; speedup 1.0000x reference)
//
#include <hip/hip_runtime.h>
#include <math.h>

#define BB 8
#define NN 512
#define DD 512
#define HH 8
#define DHH 64
#define FFF 2048
#define MEMM 4096
#define TOPKK 32
#define DEPTHH 6
#define NT (BB*NN)   /* 4096 tokens */

// ---------------- LayerNorm ----------------
__global__ __launch_bounds__(256) void ln_kernel(const float* __restrict__ xin,
                                                 const float* __restrict__ g,
                                                 const float* __restrict__ bt,
                                                 float* __restrict__ out) {
  __shared__ float red[4];
  int tok = blockIdx.x;
  const float* xr = xin + (size_t)tok * DD;
  int t = threadIdx.x;
  float v0 = xr[t], v1 = xr[t + 256];
  float s = v0 + v1;
#pragma unroll
  for (int m = 32; m; m >>= 1) s += __shfl_xor(s, m, 64);
  if ((t & 63) == 0) red[t >> 6] = s;
  __syncthreads();
  float mean = (red[0] + red[1] + red[2] + red[3]) * (1.0f / 512.0f);
  float d0 = v0 - mean, d1 = v1 - mean;
  float vv = d0 * d0 + d1 * d1;
#pragma unroll
  for (int m = 32; m; m >>= 1) vv += __shfl_xor(vv, m, 64);
  __syncthreads();
  if ((t & 63) == 0) red[t >> 6] = vv;
  __syncthreads();
  float var = (red[0] + red[1] + red[2] + red[3]) * (1.0f / 512.0f);
  float inv = rsqrtf(var + 1e-5f);
  out[(size_t)tok * DD + t]       = d0 * inv * g[t] + bt[t];
  out[(size_t)tok * DD + t + 256] = d1 * inv * g[t + 256] + bt[t + 256];
}

__device__ inline float gelu_f(float x) {
  float x3 = x * x * x;
  return 0.5f * x * (1.0f + tanhf(0.7978845608028654f * (x + 0.044715f * x3)));
}

// ---------------- SGEMM: C = A(MxK) @ B(KxN) [EPI: 0 none, 1 gelu, 2 +R] ----
template <int EPI>
__global__ __launch_bounds__(256) void gemm_kernel(const float* __restrict__ A,
                                                   const float* __restrict__ Bm,
                                                   const float* __restrict__ R,
                                                   float* __restrict__ C,
                                                   int M, int Nc, int K) {
  __shared__ float As[16][68];
  __shared__ float Bs[16][68];
  int tx = threadIdx.x & 15, ty = threadIdx.x >> 4;
  int bm = blockIdx.y, bn = blockIdx.x;
  int r0 = ty * 4, c0 = tx * 4;
  float acc[4][4] = {};
  for (int kt = 0; kt < K; kt += 16) {
    {  // A tile 64x16 -> As[k][row] (transposed)
      int row = threadIdx.x >> 2;
      int kk = (threadIdx.x & 3) * 4;
      float4 a4 = *(const float4*)(A + (size_t)(bm * 64 + row) * K + kt + kk);
      As[kk + 0][row] = a4.x; As[kk + 1][row] = a4.y;
      As[kk + 2][row] = a4.z; As[kk + 3][row] = a4.w;
    }
    {  // B tile 16x64 -> Bs[k][col]
      int kk = threadIdx.x >> 4;
      int col = (threadIdx.x & 15) * 4;
      *(float4*)&Bs[kk][col] = *(const float4*)(Bm + (size_t)(kt + kk) * Nc + bn * 64 + col);
    }
    __syncthreads();
#pragma unroll
    for (int kk = 0; kk < 16; kk++) {
      float4 a4 = *(const float4*)&As[kk][r0];
      float4 b4 = *(const float4*)&Bs[kk][c0];
      float a_[4] = {a4.x, a4.y, a4.z, a4.w};
      float b_[4] = {b4.x, b4.y, b4.z, b4.w};
#pragma unroll
      for (int i = 0; i < 4; i++)
#pragma unroll
        for (int j = 0; j < 4; j++) acc[i][j] += a_[i] * b_[j];
    }
    __syncthreads();
  }
#pragma unroll
  for (int i = 0; i < 4; i++) {
    size_t off = (size_t)(bm * 64 + r0 + i) * Nc + bn * 64 + c0;
    float4 o;
    if (EPI == 1) {
      o.x = gelu_f(acc[i][0]); o.y = gelu_f(acc[i][1]);
      o.z = gelu_f(acc[i][2]); o.w = gelu_f(acc[i][3]);
    } else if (EPI == 2) {
      float4 rv = *(const float4*)(R + off);
      o.x = rv.x + acc[i][0]; o.y = rv.y + acc[i][1];
      o.z = rv.z + acc[i][2]; o.w = rv.w + acc[i][3];
    } else {
      o.x = acc[i][0]; o.y = acc[i][1]; o.z = acc[i][2]; o.w = acc[i][3];
    }
    *(float4*)(C + off) = o;
  }
}

// ---------------- fused q@mem_k + top-32 (rewritten) ----------------
// grid (N/64, H, B) = (8,8,8), block 256.
// Per block: 64 query rows, stream mem_k in 128-candidate tiles.
// Score phase: 4x8 register microtile (FMA-bound). Scores written into the
// dead ksT buffer; wave 0 (1 lane per row) does threshold-filtered
// replace-min selection with bank-rotated reads.
__global__ __launch_bounds__(256) void knn_topk_kernel(const float* __restrict__ q,
                                                       const float* __restrict__ mem_k,
                                                       float* __restrict__ topv,
                                                       int* __restrict__ topi) {
  __shared__ float qsT[64][68];     // [d][row]
  __shared__ float ksT[64][132];    // [d][cand]; reused as scores [row][132]
  __shared__ float tv[64][33];      // top-32 values (padded: bank (r+k)%32)
  __shared__ unsigned short ti[64][33];
  int it = blockIdx.x, h = blockIdx.y, b = blockIdx.z;
  int t = threadIdx.x;
  const float scale = 0.125f;
  {  // stage q tile 64x64 transposed
    int row = t >> 2;
    int d0 = (t & 3) * 16;
    const float* qp = q + ((size_t)(b * NN) + it * 64 + row) * DD + h * DHH + d0;
#pragma unroll
    for (int j = 0; j < 16; j += 4) {
      float4 a = *(const float4*)(qp + j);
      qsT[d0 + j + 0][row] = a.x; qsT[d0 + j + 1][row] = a.y;
      qsT[d0 + j + 2][row] = a.z; qsT[d0 + j + 3][row] = a.w;
    }
  }
  int tx = t & 15, ty = t >> 4;
  int r0 = ty * 4, c0 = tx * 8;
  float thr = -INFINITY;            // lane-local 32nd value (valid for t<64)
  float* scb = &ksT[0][0];
  const float* kbase = mem_k + (size_t)b * MEMM * DHH;
  for (int mt = 0; mt < MEMM; mt += 128) {
    __syncthreads();  // prev selection done before restaging ksT
    {  // stage mem_k tile 128x64 transposed (flat-coalesced global reads)
      const float* kp = kbase + (size_t)mt * DHH;
#pragma unroll
      for (int i = 0; i < 8; i++) {
        int f = i * 1024 + t * 4;
        int cand = f >> 6, dd = f & 63;
        float4 a = *(const float4*)(kp + f);
        ksT[dd + 0][cand] = a.x; ksT[dd + 1][cand] = a.y;
        ksT[dd + 2][cand] = a.z; ksT[dd + 3][cand] = a.w;
      }
    }
    __syncthreads();
    float acc[4][8] = {};
#pragma unroll 4
    for (int d = 0; d < 64; d++) {
      float4 a4 = *(const float4*)&qsT[d][r0];
      float4 b4 = *(const float4*)&ksT[d][c0];
      float4 b5 = *(const float4*)&ksT[d][c0 + 4];
      float aa[4] = {a4.x, a4.y, a4.z, a4.w};
      float bb[8] = {b4.x, b4.y, b4.z, b4.w, b5.x, b5.y, b5.z, b5.w};
#pragma unroll
      for (int i2 = 0; i2 < 4; i2++)
#pragma unroll
        for (int j2 = 0; j2 < 8; j2++) acc[i2][j2] += aa[i2] * bb[j2];
    }
    __syncthreads();  // all waves done reading ksT
#pragma unroll
    for (int i2 = 0; i2 < 4; i2++) {  // scores -> scb (alias of ksT)
      float* p = scb + (size_t)(r0 + i2) * 132 + c0;
#pragma unroll
      for (int j2 = 0; j2 < 8; j2 += 4) {
        float4 o;
        o.x = acc[i2][j2 + 0] * scale; o.y = acc[i2][j2 + 1] * scale;
        o.z = acc[i2][j2 + 2] * scale; o.w = acc[i2][j2 + 3] * scale;
        *(float4*)(p + j2) = o;
      }
    }
    __syncthreads();
    if (t < 64) {  // selection: lane r owns row r
      int r = t;
      const float* srow = scb + (size_t)r * 132;
      if (mt == 0) {
        // warm start: slots <- cands 0..31 (rotated for conflict-free banks)
        float mn = INFINITY;
#pragma unroll
        for (int k2 = 0; k2 < 32; k2++) {
          int cand = (k2 + r) & 31;
          float v = srow[cand];
          tv[r][k2] = v; ti[r][k2] = (unsigned short)cand;
          mn = fminf(mn, v);
        }
        thr = mn;
        for (int c = 0; c < 96; c++) {
          int cc = c + (r & 31); if (cc >= 96) cc -= 96;
          int cand = 32 + cc;
          float sv = srow[cand];
          if (sv > thr) {
            int mi = 0; float mv = tv[r][0], mv2 = INFINITY;
#pragma unroll
            for (int k2 = 1; k2 < 32; k2++) {
              float v = tv[r][k2];
              if (v < mv) { mv2 = mv; mv = v; mi = k2; }
              else if (v < mv2) mv2 = v;
            }
            tv[r][mi] = sv; ti[r][mi] = (unsigned short)cand;
            thr = fminf(mv2, sv);
          }
        }
      } else {
        for (int c = 0; c < 128; c++) {
          int cand = (c + r) & 127;
          float sv = srow[cand];
          if (sv > thr) {
            int mi = 0; float mv = tv[r][0], mv2 = INFINITY;
#pragma unroll
            for (int k2 = 1; k2 < 32; k2++) {
              float v = tv[r][k2];
              if (v < mv) { mv2 = mv; mv = v; mi = k2; }
              else if (v < mv2) mv2 = v;
            }
            tv[r][mi] = sv; ti[r][mi] = (unsigned short)(mt + cand);
            thr = fminf(mv2, sv);
          }
        }
      }
    }
  }
  __syncthreads();
  if (t < 64) {
    size_t rowg = ((size_t)b * HH + h) * NN + it * 64 + t;
#pragma unroll
    for (int k2 = 0; k2 < 32; k2++) {
      topv[rowg * TOPKK + k2] = tv[t][k2];
      topi[rowg * TOPKK + k2] = (int)ti[t][k2];
    }
  }
}

// ---------------- flash attention (+ optional kNN memory logits) ----------
// grid (N/64, H, B), block 256. ao layout [b][i][h*64+d]
__global__ __launch_bounds__(256) void attn_kernel(const float* __restrict__ q,
                                                   const float* __restrict__ k,
                                                   const float* __restrict__ v,
                                                   float* __restrict__ ao,
                                                   const float* __restrict__ topv,
                                                   const int* __restrict__ topi,
                                                   const float* __restrict__ mem_v,
                                                   int knn) {
  int bi = blockIdx.x, h = blockIdx.y, b = blockIdx.z;
  __shared__ float ks[64][64];
  __shared__ float vs[64][64];
  __shared__ float sc[64][65];
  __shared__ float marr[64], larr[64], aarr[64];
  __shared__ int pidx[64][33];
  const float scale = 0.125f;
  int t = threadIdx.x;
  int r = t & 63;   // row role
  int w = t >> 6;   // wave: phase1 col-group / phase2 d-group
  int i0 = bi * 64;
  int iglob = i0 + r;

  float qreg[64];
  {
    const float* qp = q + ((size_t)(b * NN) + iglob) * DD + h * DHH;
#pragma unroll
    for (int d4 = 0; d4 < 64; d4 += 4) {
      float4 a = *(const float4*)(qp + d4);
      qreg[d4] = a.x * scale; qreg[d4 + 1] = a.y * scale;
      qreg[d4 + 2] = a.z * scale; qreg[d4 + 3] = a.w * scale;
    }
  }
  if (t < 64) { marr[t] = -INFINITY; larr[t] = 0.f; }
  float acc[16] = {};
  int ntiles = bi + 1;
  for (int jt = 0; jt < ntiles; jt++) {
    __syncthreads();
#pragma unroll
    for (int i = 0; i < 4; i++) {  // load K,V tiles
      int lin = i * 256 + t;
      int row = lin >> 4, col = (lin & 15) * 4;
      size_t goff = ((size_t)(b * NN) + jt * 64 + row) * DD + h * DHH + col;
      *(float4*)&ks[row][col] = *(const float4*)(k + goff);
      *(float4*)&vs[row][col] = *(const float4*)(v + goff);
    }
    __syncthreads();
    {  // phase1: scores row r, cols w*16..+15
      float s[16] = {};
#pragma unroll
      for (int d4 = 0; d4 < 64; d4 += 4) {
#pragma unroll
        for (int j = 0; j < 16; j++) {
          float4 k4 = *(const float4*)&ks[w * 16 + j][d4];
          s[j] += qreg[d4] * k4.x + qreg[d4 + 1] * k4.y +
                  qreg[d4 + 2] * k4.z + qreg[d4 + 3] * k4.w;
        }
      }
#pragma unroll
      for (int j = 0; j < 16; j++) sc[r][w * 16 + j] = s[j];
    }
    __syncthreads();
    {  // online softmax: wave w owns rows w*16..+15
      int lane = t & 63;
      for (int rr = w * 16; rr < w * 16 + 16; rr++) {
        int ig = i0 + rr;
        int jg = jt * 64 + lane;
        float s = sc[rr][lane];
        if (jg > ig) s = -INFINITY;
        float m_old = marr[rr];
        float tm = s;
#pragma unroll
        for (int m = 32; m; m >>= 1) tm = fmaxf(tm, __shfl_xor(tm, m, 64));
        float m_new = fmaxf(m_old, tm);
        float p = __expf(s - m_new);
        float ts = p;
#pragma unroll
        for (int m = 32; m; m >>= 1) ts += __shfl_xor(ts, m, 64);
        float alpha = __expf(m_old - m_new);
        sc[rr][lane] = p;
        if (lane == 0) {
          marr[rr] = m_new; larr[rr] = larr[rr] * alpha + ts; aarr[rr] = alpha;
        }
      }
    }
    __syncthreads();
    {  // phase2: acc[r][w*16..+15] += P @ V
      float al = aarr[r];
#pragma unroll
      for (int dd = 0; dd < 16; dd++) acc[dd] *= al;
      for (int j = 0; j < 64; j++) {
        float p = sc[r][j];
        const float* vrow = &vs[j][w * 16];
#pragma unroll
        for (int dd = 0; dd < 16; dd += 4) {
          float4 v4 = *(const float4*)(vrow + dd);
          acc[dd] += p * v4.x; acc[dd + 1] += p * v4.y;
          acc[dd + 2] += p * v4.z; acc[dd + 3] += p * v4.w;
        }
      }
    }
  }
  if (knn) {
    __syncthreads();
    {  // memory logits (already scaled in topk kernel)
      int lane = t & 63;
      size_t rowbase = ((size_t)b * HH + h) * NN + i0;
      for (int rr = w * 16; rr < w * 16 + 16; rr++) {
        float s = (lane < TOPKK) ? topv[(rowbase + rr) * TOPKK + lane] : -INFINITY;
        float m_old = marr[rr];
        float tm = s;
#pragma unroll
        for (int m = 32; m; m >>= 1) tm = fmaxf(tm, __shfl_xor(tm, m, 64));
        float m_new = fmaxf(m_old, tm);
        float p = __expf(s - m_new);
        float ts = p;
#pragma unroll
        for (int m = 32; m; m >>= 1) ts += __shfl_xor(ts, m, 64);
        float alpha = __expf(m_old - m_new);
        sc[rr][lane] = p;
        if (lane < TOPKK) pidx[rr][lane] = topi[(rowbase + rr) * TOPKK + lane];
        if (lane == 0) {
          marr[rr] = m_new; larr[rr] = larr[rr] * alpha + ts; aarr[rr] = alpha;
        }
      }
    }
    __syncthreads();
    {
      float al = aarr[r];
#pragma unroll
      for (int dd = 0; dd < 16; dd++) acc[dd] *= al;
      const float* mvb = mem_v + (size_t)b * MEMM * DHH;
      for (int kk = 0; kk < TOPKK; kk++) {
        float p = sc[r][kk];
        const float* mrow = mvb + (size_t)pidx[r][kk] * DHH + w * 16;
#pragma unroll
        for (int dd = 0; dd < 16; dd += 4) {
          float4 m4 = *(const float4*)(mrow + dd);
          acc[dd] += p * m4.x; acc[dd + 1] += p * m4.y;
          acc[dd + 2] += p * m4.z; acc[dd + 3] += p * m4.w;
        }
      }
    }
  }
  {  // epilogue: out = acc / l
    float linv = 1.0f / larr[r];
    float* aop = ao + ((size_t)(b * NN) + iglob) * DD + h * DHH + w * 16;
#pragma unroll
    for (int dd = 0; dd < 16; dd += 4) {
      float4 o;
      o.x = acc[dd] * linv; o.y = acc[dd + 1] * linv;
      o.z = acc[dd + 2] * linv; o.w = acc[dd + 3] * linv;
      *(float4*)(aop + dd) = o;
    }
  }
}

// ---------------- host ----------------
extern "C" void kernel_launch(void* const* d_in, const int* in_sizes, int n_in,
                              void* d_out, int out_size, void* d_ws, size_t ws_size,
                              hipStream_t stream) {
  const float* x_in  = (const float*)d_in[0];
  const float* Wq    = (const float*)d_in[1];
  const float* Wk    = (const float*)d_in[2];
  const float* Wv    = (const float*)d_in[3];
  const float* Wo    = (const float*)d_in[4];
  const float* ln1_s = (const float*)d_in[5];
  const float* ln1_b = (const float*)d_in[6];
  const float* ln2_s = (const float*)d_in[7];
  const float* ln2_b = (const float*)d_in[8];
  const float* W1    = (const float*)d_in[9];
  const float* W2    = (const float*)d_in[10];
  const float* lnf_s = (const float*)d_in[11];
  const float* lnf_b = (const float*)d_in[12];
  const float* mem_k = (const float*)d_in[13];
  const float* mem_v = (const float*)d_in[14];

  // workspace layout (floats), total 14,680,064 floats = 58.72 MB:
  //  xb   [0        .. 2097152)   residual stream
  //  hb   [2097152  .. 4194304)   LN output
  //  qb/kb/vb/aob [4194304 .. 12582912)  (ffb 32MB aliases these during FFN)
  //  tvb  [12582912 .. 13631488)  top-k values  (B*H*N*TOPK = 1M elems)
  //  tib  [13631488 .. 14680064)  top-k indices (1M elems)
  float* ws  = (float*)d_ws;
  float* xb  = ws;
  float* hb  = ws + 2097152;
  float* qb  = ws + 4194304;
  float* kb  = ws + 6291456;
  float* vb  = ws + 8388608;
  float* aob = ws + 10485760;
  float* ffb = ws + 4194304;           // aliases qb..aob
  float* tvb = ws + 12582912;
  int*   tib = (int*)(ws + 13631488);

  dim3 blk(256);
  const size_t DD2 = (size_t)DD * DD;
  for (int l = 0; l < DEPTHH; l++) {
    const float* xcur = (l == 0) ? x_in : xb;
    ln_kernel<<<NT, blk, 0, stream>>>(xcur, ln1_s + l * DD, ln1_b + l * DD, hb);
    gemm_kernel<0><<<dim3(8, 64), blk, 0, stream>>>(hb, Wq + l * DD2, nullptr, qb, NT, DD, DD);
    gemm_kernel<0><<<dim3(8, 64), blk, 0, stream>>>(hb, Wk + l * DD2, nullptr, kb, NT, DD, DD);
    gemm_kernel<0><<<dim3(8, 64), blk, 0, stream>>>(hb, Wv + l * DD2, nullptr, vb, NT, DD, DD);
    int mi = (l == 3) ? 0 : ((l == 4) ? 1 : -1);
    if (mi >= 0)
      knn_topk_kernel<<<dim3(8, 8, 8), blk, 0, stream>>>(
          qb, mem_k + (size_t)mi * BB * MEMM * DHH, tvb, tib);
    attn_kernel<<<dim3(8, 8, 8), blk, 0, stream>>>(
        qb, kb, vb, aob, tvb, tib,
        mem_v + (size_t)(mi < 0 ? 0 : mi) * BB * MEMM * DHH, mi >= 0 ? 1 : 0);
    gemm_kernel<2><<<dim3(8, 64), blk, 0, stream>>>(aob, Wo + l * DD2, xcur, xb, NT, DD, DD);
    ln_kernel<<<NT, blk, 0, stream>>>(xb, ln2_s + l * DD, ln2_b + l * DD, hb);
    gemm_kernel<1><<<dim3(32, 64), blk, 0, stream>>>(
        hb, W1 + (size_t)l * DD * FFF, nullptr, ffb, NT, FFF, DD);
    gemm_kernel<2><<<dim3(8, 64), blk, 0, stream>>>(
        ffb, W2 + (size_t)l * FFF * DD, xb, xb, NT, DD, FFF);
  }
  ln_kernel<<<NT, blk, 0, stream>>>(xb, lnf_s, lnf_b, (float*)d_out);
}